// Round 1
// baseline (368.524 us; speedup 1.0000x reference)
//
#include <hip/hip_runtime.h>
#include <hip/hip_bf16.h>

#define MODEL 1024
#define NHEADS 16
#define HDIM 64
#define BATCH 2
#define SEQ 2048
#define NROWS (BATCH*SEQ)   // 4096
#define QKVN (3*MODEL)      // 3072

typedef __bf16 bf16x8 __attribute__((ext_vector_type(8)));
typedef float f32x4 __attribute__((ext_vector_type(4)));

#define GLDS(g, l) __builtin_amdgcn_global_load_lds( \
    (const __attribute__((address_space(1))) void*)(g), \
    (__attribute__((address_space(3))) void*)(l), 16, 0, 0)

// ---------------- converters ----------------

__global__ __launch_bounds__(256) void cvt_bf16_kernel(const float* __restrict__ in,
                                                       __hip_bfloat16* __restrict__ out, int n) {
    int i = (blockIdx.x * 256 + threadIdx.x) * 4;
    if (i < n) {
        float4 v = *(const float4*)(in + i);
        out[i + 0] = __float2bfloat16(v.x);
        out[i + 1] = __float2bfloat16(v.y);
        out[i + 2] = __float2bfloat16(v.z);
        out[i + 3] = __float2bfloat16(v.w);
    }
}

// in[K][N] f32 -> out[N][K] bf16
__global__ __launch_bounds__(256) void tcvt_kernel(const float* __restrict__ in,
                                                   __hip_bfloat16* __restrict__ out, int K, int N) {
    __shared__ float tile[32][33];
    int tx = threadIdx.x, ty = threadIdx.y;
    int n0 = blockIdx.x * 32, k0 = blockIdx.y * 32;
#pragma unroll
    for (int i = 0; i < 4; ++i)
        tile[ty + i * 8][tx] = in[(size_t)(k0 + ty + i * 8) * N + n0 + tx];
    __syncthreads();
#pragma unroll
    for (int i = 0; i < 4; ++i)
        out[(size_t)(n0 + ty + i * 8) * K + k0 + tx] = __float2bfloat16(tile[tx][ty + i * 8]);
}

// ---------------- GEMM: C[M,N] = A[M,K] @ Bt[N,K]^T + bias ----------------
// EPI 0: scatter to q/k/v bf16 buffers [B,H,S,64]; EPI 1: fp32 C + bias.

template<int EPI>
__global__ __launch_bounds__(256) void gemm_bt_kernel(
    const __hip_bfloat16* __restrict__ A, const __hip_bfloat16* __restrict__ Bt,
    const float* __restrict__ bias, float* __restrict__ Cf,
    __hip_bfloat16* __restrict__ qb, __hip_bfloat16* __restrict__ kb,
    __hip_bfloat16* __restrict__ vb, int M, int N, int K)
{
    __shared__ __hip_bfloat16 As[128 * 32];
    __shared__ __hip_bfloat16 Bs[128 * 32];
    int tid = threadIdx.x;
    int lane = tid & 63, wv = tid >> 6;
    int wm = wv >> 1, wn = wv & 1;
    int g = lane >> 4, li = lane & 15;
    int row0 = blockIdx.y * 128, col0 = blockIdx.x * 128;

    f32x4 acc[4][4] = {};

    for (int kt = 0; kt < K; kt += 32) {
        __syncthreads();
#pragma unroll
        for (int s = 0; s < 2; ++s) {
            int idx = (s * 256 + tid) * 8;
            int r = idx >> 5, c = idx & 31;
            const __hip_bfloat16* ga = A + (size_t)(row0 + r) * K + kt + c;
            char* la = (char*)As + (size_t)(s * 4 + wv) * 1024;
            GLDS(ga, la);
            const __hip_bfloat16* gb = Bt + (size_t)(col0 + r) * K + kt + c;
            char* lb = (char*)Bs + (size_t)(s * 4 + wv) * 1024;
            GLDS(gb, lb);
        }
        __syncthreads();
        bf16x8 a[4], b[4];
#pragma unroll
        for (int m = 0; m < 4; ++m)
            a[m] = *(const bf16x8*)((const char*)As + (size_t)((wm * 64 + m * 16 + li) * 32 + g * 8) * 2);
#pragma unroll
        for (int n = 0; n < 4; ++n)
            b[n] = *(const bf16x8*)((const char*)Bs + (size_t)((wn * 64 + n * 16 + li) * 32 + g * 8) * 2);
#pragma unroll
        for (int m = 0; m < 4; ++m)
#pragma unroll
            for (int n = 0; n < 4; ++n)
                acc[m][n] = __builtin_amdgcn_mfma_f32_16x16x32_bf16(a[m], b[n], acc[m][n], 0, 0, 0);
    }

    if (EPI == 1) {
#pragma unroll
        for (int m = 0; m < 4; ++m) {
            int row = row0 + wm * 64 + m * 16 + g * 4;
#pragma unroll
            for (int n = 0; n < 4; ++n) {
                int col = col0 + wn * 64 + n * 16 + li;
                float bv = bias[col];
#pragma unroll
                for (int r = 0; r < 4; ++r)
                    Cf[(size_t)(row + r) * N + col] = acc[m][n][r] + bv;
            }
        }
    } else {
#pragma unroll
        for (int m = 0; m < 4; ++m)
#pragma unroll
            for (int r = 0; r < 4; ++r) {
                int row = row0 + wm * 64 + m * 16 + g * 4 + r;
                int b = row >> 11, s = row & 2047;
#pragma unroll
                for (int n = 0; n < 4; ++n) {
                    int col = col0 + wn * 64 + n * 16 + li;
                    float val = acc[m][n][r] + bias[col];
                    int h = col / 192;
                    int rem = col - h * 192;
                    int t = rem >> 6, d = rem & 63;
                    __hip_bfloat16* dst = (t == 0) ? qb : ((t == 1) ? kb : vb);
                    dst[((size_t)(b * NHEADS + h) * SEQ + s) * HDIM + d] = __float2bfloat16(val);
                }
            }
    }
}

// ---------------- flash attention ----------------
// grid: (SEQ/64, BATCH*NHEADS), 256 threads (4 waves, 16 q-rows each), KVBLK=32

__global__ __launch_bounds__(256) void attn_kernel(
    const __hip_bfloat16* __restrict__ qb, const __hip_bfloat16* __restrict__ kb,
    const __hip_bfloat16* __restrict__ vb, __hip_bfloat16* __restrict__ ctx)
{
    __shared__ unsigned short Vt[64][56];    // V^T tile, 112B rows: 2-way bank alias only
    __shared__ unsigned short Pl[4][16][56]; // per-wave P transpose buffer
    int tid = threadIdx.x, lane = tid & 63, w = tid >> 6;
    int g = lane >> 4, li = lane & 15;
    int bh = blockIdx.y, qt = blockIdx.x;
    int b = bh >> 4, h = bh & 15;
    const __hip_bfloat16* Q = qb + (size_t)bh * SEQ * HDIM;
    const __hip_bfloat16* Kp = kb + (size_t)bh * SEQ * HDIM;
    const __hip_bfloat16* V = vb + (size_t)bh * SEQ * HDIM;

    int qrow = qt * 64 + w * 16 + li;
    bf16x8 qf[2];
    qf[0] = *(const bf16x8*)(Q + (size_t)qrow * HDIM + g * 8);
    qf[1] = *(const bf16x8*)(Q + (size_t)qrow * HDIM + 32 + g * 8);

    f32x4 o[4] = {};
    float mr[4] = {-1e30f, -1e30f, -1e30f, -1e30f};
    float lr[4] = {0.f, 0.f, 0.f, 0.f};

    for (int kv0 = 0; kv0 < SEQ; kv0 += 32) {
        __syncthreads();  // prior iteration done reading Vt
        {
            int idx = tid * 8;
            int kv = idx >> 6, d0 = idx & 63;
            int4 vv = *(const int4*)(V + (size_t)(kv0 + kv) * HDIM + d0);
            unsigned short* vs = (unsigned short*)&vv;
#pragma unroll
            for (int jj = 0; jj < 8; ++jj)
                Vt[d0 + jj][kv] = vs[jj];
        }
        __syncthreads();

        f32x4 sc[2] = {};
#pragma unroll
        for (int nf = 0; nf < 2; ++nf)
#pragma unroll
            for (int kf = 0; kf < 2; ++kf) {
                bf16x8 kfr = *(const bf16x8*)(Kp + (size_t)(kv0 + nf * 16 + li) * HDIM + kf * 32 + g * 8);
                sc[nf] = __builtin_amdgcn_mfma_f32_16x16x32_bf16(qf[kf], kfr, sc[nf], 0, 0, 0);
            }

#pragma unroll
        for (int r = 0; r < 4; ++r) {
            float s0 = sc[0][r] * 0.125f, s1 = sc[1][r] * 0.125f;
            float mx = fmaxf(s0, s1);
            mx = fmaxf(mx, __shfl_xor(mx, 1));
            mx = fmaxf(mx, __shfl_xor(mx, 2));
            mx = fmaxf(mx, __shfl_xor(mx, 4));
            mx = fmaxf(mx, __shfl_xor(mx, 8));
            float mnew = fmaxf(mr[r], mx);
            float alpha = __expf(mr[r] - mnew);
            float p0 = __expf(s0 - mnew), p1 = __expf(s1 - mnew);
            float ps = p0 + p1;
            ps += __shfl_xor(ps, 1);
            ps += __shfl_xor(ps, 2);
            ps += __shfl_xor(ps, 4);
            ps += __shfl_xor(ps, 8);
            lr[r] = lr[r] * alpha + ps;
            mr[r] = mnew;
#pragma unroll
            for (int n = 0; n < 4; ++n) o[n][r] *= alpha;
            int q = g * 4 + r;
            Pl[w][q][li] = __builtin_bit_cast(unsigned short, __float2bfloat16(p0));
            Pl[w][q][16 + li] = __builtin_bit_cast(unsigned short, __float2bfloat16(p1));
        }
        // wave-internal LDS: compiler inserts lgkmcnt waits (same array aliasing)
        bf16x8 pf = *(const bf16x8*)(&Pl[w][li][g * 8]);
#pragma unroll
        for (int n = 0; n < 4; ++n) {
            bf16x8 vf = *(const bf16x8*)(&Vt[n * 16 + li][g * 8]);
            o[n] = __builtin_amdgcn_mfma_f32_16x16x32_bf16(pf, vf, o[n], 0, 0, 0);
        }
    }

#pragma unroll
    for (int r = 0; r < 4; ++r) {
        float inv = 1.0f / lr[r];
        int q = qt * 64 + w * 16 + g * 4 + r;
        size_t base = ((size_t)(b * SEQ) + q) * MODEL + (size_t)h * HDIM;
#pragma unroll
        for (int n = 0; n < 4; ++n)
            ctx[base + n * 16 + li] = __float2bfloat16(o[n][r] * inv);
    }
}

// ---------------- launch ----------------

extern "C" void kernel_launch(void* const* d_in, const int* in_sizes, int n_in,
                              void* d_out, int out_size, void* d_ws, size_t ws_size,
                              hipStream_t stream) {
    const float* emb = (const float*)d_in[0];
    const float* w_qkv = (const float*)d_in[1];
    const float* b_qkv = (const float*)d_in[2];
    const float* w_out = (const float*)d_in[3];
    const float* b_out = (const float*)d_in[4];
    float* out = (float*)d_out;
    char* ws = (char*)d_ws;

    __hip_bfloat16* Xb    = (__hip_bfloat16*)(ws);                       //  8 MB
    __hip_bfloat16* Wqkvt = (__hip_bfloat16*)(ws + ((size_t)8  << 20));  //  6 MB
    __hip_bfloat16* Woutt = (__hip_bfloat16*)(ws + ((size_t)14 << 20));  //  2 MB
    __hip_bfloat16* qbuf  = (__hip_bfloat16*)(ws + ((size_t)16 << 20));  //  8 MB
    __hip_bfloat16* kbuf  = (__hip_bfloat16*)(ws + ((size_t)24 << 20));  //  8 MB
    __hip_bfloat16* vbuf  = (__hip_bfloat16*)(ws + ((size_t)32 << 20));  //  8 MB
    __hip_bfloat16* ctx   = (__hip_bfloat16*)(ws + ((size_t)40 << 20));  //  8 MB

    cvt_bf16_kernel<<<4096, 256, 0, stream>>>(emb, Xb, NROWS * MODEL);
    tcvt_kernel<<<dim3(QKVN / 32, MODEL / 32), dim3(32, 8), 0, stream>>>(w_qkv, Wqkvt, MODEL, QKVN);
    tcvt_kernel<<<dim3(MODEL / 32, MODEL / 32), dim3(32, 8), 0, stream>>>(w_out, Woutt, MODEL, MODEL);

    gemm_bt_kernel<0><<<dim3(QKVN / 128, NROWS / 128), 256, 0, stream>>>(
        Xb, Wqkvt, b_qkv, nullptr, qbuf, kbuf, vbuf, NROWS, QKVN, MODEL);

    attn_kernel<<<dim3(SEQ / 64, BATCH * NHEADS), 256, 0, stream>>>(qbuf, kbuf, vbuf, ctx);

    gemm_bt_kernel<1><<<dim3(MODEL / 128, NROWS / 128), 256, 0, stream>>>(
        ctx, Woutt, b_out, out, nullptr, nullptr, nullptr, NROWS, MODEL, MODEL);
}

// Round 2
// 283.423 us; speedup vs baseline: 1.3003x; 1.3003x over previous
//
#include <hip/hip_runtime.h>
#include <hip/hip_bf16.h>

#define MODEL 1024
#define NHEADS 16
#define HDIM 64
#define BATCH 2
#define SEQ 2048
#define NROWS (BATCH*SEQ)   // 4096
#define QKVN (3*MODEL)      // 3072
#define QSCALE 0.1803368801111204f  // 0.125 * log2(e): folded into Q; softmax uses exp2

typedef __bf16 bf16x8 __attribute__((ext_vector_type(8)));
typedef float f32x4 __attribute__((ext_vector_type(4)));
typedef float f32x16 __attribute__((ext_vector_type(16)));

#define GLDS(g, l) __builtin_amdgcn_global_load_lds( \
    (const __attribute__((address_space(1))) void*)(g), \
    (__attribute__((address_space(3))) void*)(l), 16, 0, 0)

__device__ inline unsigned cvtpk(float a, float b) {
    unsigned la = __builtin_bit_cast(unsigned short, __float2bfloat16(a));
    unsigned hb = __builtin_bit_cast(unsigned short, __float2bfloat16(b));
    return la | (hb << 16);
}

// ---------------- converters ----------------

__global__ __launch_bounds__(256) void cvt_bf16_kernel(const float* __restrict__ in,
                                                       __hip_bfloat16* __restrict__ out, int n) {
    int i = (blockIdx.x * 256 + threadIdx.x) * 4;
    if (i < n) {
        float4 v = *(const float4*)(in + i);
        out[i + 0] = __float2bfloat16(v.x);
        out[i + 1] = __float2bfloat16(v.y);
        out[i + 2] = __float2bfloat16(v.z);
        out[i + 3] = __float2bfloat16(v.w);
    }
}

// in[K][N] f32 -> out[N][K] bf16
__global__ __launch_bounds__(256) void tcvt_kernel(const float* __restrict__ in,
                                                   __hip_bfloat16* __restrict__ out, int K, int N) {
    __shared__ float tile[32][33];
    int tx = threadIdx.x, ty = threadIdx.y;
    int n0 = blockIdx.x * 32, k0 = blockIdx.y * 32;
#pragma unroll
    for (int i = 0; i < 4; ++i)
        tile[ty + i * 8][tx] = in[(size_t)(k0 + ty + i * 8) * N + n0 + tx];
    __syncthreads();
#pragma unroll
    for (int i = 0; i < 4; ++i)
        out[(size_t)(n0 + ty + i * 8) * K + k0 + tx] = __float2bfloat16(tile[tx][ty + i * 8]);
}

// ---------------- GEMM: C[M,N] = A[M,K] @ Bt[N,K]^T + bias ----------------
// EPI 0: scatter to q (scaled) / k [B,H,S,64] and v TRANSPOSED [B,H,64,S]; EPI 1: fp32 C + bias.

template<int EPI>
__global__ __launch_bounds__(256) void gemm_bt_kernel(
    const __hip_bfloat16* __restrict__ A, const __hip_bfloat16* __restrict__ Bt,
    const float* __restrict__ bias, float* __restrict__ Cf,
    __hip_bfloat16* __restrict__ qb, __hip_bfloat16* __restrict__ kb,
    __hip_bfloat16* __restrict__ vb, int M, int N, int K)
{
    __shared__ __hip_bfloat16 As[128 * 32];
    __shared__ __hip_bfloat16 Bs[128 * 32];
    int tid = threadIdx.x;
    int lane = tid & 63, wv = tid >> 6;
    int wm = wv >> 1, wn = wv & 1;
    int g = lane >> 4, li = lane & 15;
    int row0 = blockIdx.y * 128, col0 = blockIdx.x * 128;

    f32x4 acc[4][4] = {};

    for (int kt = 0; kt < K; kt += 32) {
        __syncthreads();
#pragma unroll
        for (int s = 0; s < 2; ++s) {
            int idx = (s * 256 + tid) * 8;
            int r = idx >> 5, c = idx & 31;
            const __hip_bfloat16* ga = A + (size_t)(row0 + r) * K + kt + c;
            char* la = (char*)As + (size_t)(s * 4 + wv) * 1024;
            GLDS(ga, la);
            const __hip_bfloat16* gb = Bt + (size_t)(col0 + r) * K + kt + c;
            char* lb = (char*)Bs + (size_t)(s * 4 + wv) * 1024;
            GLDS(gb, lb);
        }
        __syncthreads();
        bf16x8 a[4], b[4];
#pragma unroll
        for (int m = 0; m < 4; ++m)
            a[m] = *(const bf16x8*)((const char*)As + (size_t)((wm * 64 + m * 16 + li) * 32 + g * 8) * 2);
#pragma unroll
        for (int n = 0; n < 4; ++n)
            b[n] = *(const bf16x8*)((const char*)Bs + (size_t)((wn * 64 + n * 16 + li) * 32 + g * 8) * 2);
#pragma unroll
        for (int m = 0; m < 4; ++m)
#pragma unroll
            for (int n = 0; n < 4; ++n)
                acc[m][n] = __builtin_amdgcn_mfma_f32_16x16x32_bf16(a[m], b[n], acc[m][n], 0, 0, 0);
    }

    if (EPI == 1) {
#pragma unroll
        for (int m = 0; m < 4; ++m) {
            int row = row0 + wm * 64 + m * 16 + g * 4;
#pragma unroll
            for (int n = 0; n < 4; ++n) {
                int col = col0 + wn * 64 + n * 16 + li;
                float bv = bias[col];
#pragma unroll
                for (int r = 0; r < 4; ++r)
                    Cf[(size_t)(row + r) * N + col] = acc[m][n][r] + bv;
            }
        }
    } else {
#pragma unroll
        for (int m = 0; m < 4; ++m)
#pragma unroll
            for (int r = 0; r < 4; ++r) {
                int row = row0 + wm * 64 + m * 16 + g * 4 + r;
                int b = row >> 11, s = row & 2047;
#pragma unroll
                for (int n = 0; n < 4; ++n) {
                    int col = col0 + wn * 64 + n * 16 + li;
                    float val = acc[m][n][r] + bias[col];
                    int h = col / 192;
                    int rem = col - h * 192;
                    int t = rem >> 6, d = rem & 63;
                    if (t == 0)
                        qb[((size_t)(b * NHEADS + h) * SEQ + s) * HDIM + d] = __float2bfloat16(val * QSCALE);
                    else if (t == 1)
                        kb[((size_t)(b * NHEADS + h) * SEQ + s) * HDIM + d] = __float2bfloat16(val);
                    else
                        vb[((size_t)(b * NHEADS + h) * HDIM + d) * SEQ + s] = __float2bfloat16(val);
                }
            }
    }
}

// ---------------- flash attention (swapped-QK^T, zero-LDS) ----------------
// grid: (B*H=32, SEQ/256=8), 512 threads = 8 waves, each wave owns 32 q-rows.
// Per lane: q = q0 + (lane&31) for ALL state (scores, m, l, O^T) -> softmax is
// 31 in-lane ops + one shfl_xor(32). KVBLK=64 -> 16 mfma_32x32x16 per iter.

__global__ __launch_bounds__(512, 2) void attn_kernel(
    const __hip_bfloat16* __restrict__ qb, const __hip_bfloat16* __restrict__ kb,
    const __hip_bfloat16* __restrict__ vt, __hip_bfloat16* __restrict__ ctx)
{
    int tid = threadIdx.x;
    int lane = tid & 63, w = tid >> 6;
    int qi = lane & 31, hi = lane >> 5;
    int bh = blockIdx.x;
    int b = bh >> 4, h = bh & 15;
    int q0 = blockIdx.y * 256 + w * 32;

    const __hip_bfloat16* Q = qb + (size_t)bh * SEQ * HDIM;
    const __hip_bfloat16* K = kb + (size_t)bh * SEQ * HDIM;
    const __hip_bfloat16* V = vt + (size_t)bh * HDIM * SEQ;  // V^T: [64][SEQ]

    bf16x8 qf[4];
#pragma unroll
    for (int st = 0; st < 4; ++st)
        qf[st] = *(const bf16x8*)(Q + (size_t)(q0 + qi) * HDIM + st * 16 + hi * 8);

    f32x16 o0 = {}, o1 = {};
    float m = -INFINITY, l = 0.f;

    for (int kv0 = 0; kv0 < SEQ; kv0 += 64) {
        __builtin_amdgcn_s_barrier();  // keep 8 waves lockstep for K/V L1 reuse
        // S^T[k][q] = sum_d K[k][d] * Q[q][d]  (Q pre-scaled by 0.125*log2e)
        f32x16 s0 = {}, s1 = {};
#pragma unroll
        for (int st = 0; st < 4; ++st) {
            bf16x8 kf0 = *(const bf16x8*)(K + (size_t)(kv0 + qi) * HDIM + st * 16 + hi * 8);
            bf16x8 kf1 = *(const bf16x8*)(K + (size_t)(kv0 + 32 + qi) * HDIM + st * 16 + hi * 8);
            s0 = __builtin_amdgcn_mfma_f32_32x32x16_bf16(kf0, qf[st], s0, 0, 0, 0);
            s1 = __builtin_amdgcn_mfma_f32_32x32x16_bf16(kf1, qf[st], s1, 0, 0, 0);
        }
        // online softmax in log2 domain; lane owns row q for all 32 of its k-slots
        float mx = -INFINITY;
#pragma unroll
        for (int r = 0; r < 16; ++r) mx = fmaxf(mx, fmaxf(s0[r], s1[r]));
        mx = fmaxf(mx, __shfl_xor(mx, 32));
        float mn = fmaxf(m, mx);
        float al = exp2f(m - mn);
        m = mn;
        float p[32];
        float sum = 0.f;
#pragma unroll
        for (int r = 0; r < 16; ++r) { p[r] = exp2f(s0[r] - mn); sum += p[r]; }
#pragma unroll
        for (int r = 0; r < 16; ++r) { p[16 + r] = exp2f(s1[r] - mn); sum += p[16 + r]; }
        sum += __shfl_xor(sum, 32);
        l = l * al + sum;
#pragma unroll
        for (int r = 0; r < 16; ++r) { o0[r] *= al; o1[r] *= al; }

        // redistribute P^T into B-fragments: lane needs P[q=lane&31][k=16ks+hi*8+jj]
        bf16x8 pb[4];
#pragma unroll
        for (int ks = 0; ks < 4; ++ks) {
            int base = ks * 8;
            unsigned t0 = cvtpk(p[base + 0], p[base + 1]);
            unsigned t1 = cvtpk(p[base + 2], p[base + 3]);
            unsigned u0 = cvtpk(p[base + 4], p[base + 5]);
            unsigned u1 = cvtpk(p[base + 6], p[base + 7]);
            unsigned t0s = __shfl_xor(t0, 32);
            unsigned t1s = __shfl_xor(t1, 32);
            unsigned u0s = __shfl_xor(u0, 32);
            unsigned u1s = __shfl_xor(u1, 32);
            union { unsigned u[4]; bf16x8 v; } pk;
            pk.u[0] = hi ? u0s : t0;
            pk.u[1] = hi ? u1s : t1;
            pk.u[2] = hi ? u0 : t0s;
            pk.u[3] = hi ? u1 : t1s;
            pb[ks] = pk.v;
        }
        // O^T[d][q] += V^T[d][k] @ P^T[k][q]
#pragma unroll
        for (int ks = 0; ks < 4; ++ks) {
            bf16x8 v0 = *(const bf16x8*)(V + (size_t)qi * SEQ + kv0 + ks * 16 + hi * 8);
            bf16x8 v1 = *(const bf16x8*)(V + (size_t)(32 + qi) * SEQ + kv0 + ks * 16 + hi * 8);
            o0 = __builtin_amdgcn_mfma_f32_32x32x16_bf16(v0, pb[ks], o0, 0, 0, 0);
            o1 = __builtin_amdgcn_mfma_f32_32x32x16_bf16(v1, pb[ks], o1, 0, 0, 0);
        }
    }

    // epilogue: lane holds O^T[d][q] for its q; d = dt*32 + 8*rg + 4*hi + (0..3)
    float inv = 1.f / l;
    __hip_bfloat16* crow = ctx + ((size_t)(b * SEQ) + q0 + qi) * MODEL + h * HDIM;
#pragma unroll
    for (int rg = 0; rg < 4; ++rg) {
        uint2 pk0, pk1;
        pk0.x = cvtpk(o0[rg * 4 + 0] * inv, o0[rg * 4 + 1] * inv);
        pk0.y = cvtpk(o0[rg * 4 + 2] * inv, o0[rg * 4 + 3] * inv);
        pk1.x = cvtpk(o1[rg * 4 + 0] * inv, o1[rg * 4 + 1] * inv);
        pk1.y = cvtpk(o1[rg * 4 + 2] * inv, o1[rg * 4 + 3] * inv);
        *(uint2*)(crow + rg * 8 + hi * 4) = pk0;
        *(uint2*)(crow + 32 + rg * 8 + hi * 4) = pk1;
    }
}

// ---------------- launch ----------------

extern "C" void kernel_launch(void* const* d_in, const int* in_sizes, int n_in,
                              void* d_out, int out_size, void* d_ws, size_t ws_size,
                              hipStream_t stream) {
    const float* emb = (const float*)d_in[0];
    const float* w_qkv = (const float*)d_in[1];
    const float* b_qkv = (const float*)d_in[2];
    const float* w_out = (const float*)d_in[3];
    const float* b_out = (const float*)d_in[4];
    float* out = (float*)d_out;
    char* ws = (char*)d_ws;

    __hip_bfloat16* Xb    = (__hip_bfloat16*)(ws);                       //  8 MB
    __hip_bfloat16* Wqkvt = (__hip_bfloat16*)(ws + ((size_t)8  << 20));  //  6 MB
    __hip_bfloat16* Woutt = (__hip_bfloat16*)(ws + ((size_t)14 << 20));  //  2 MB
    __hip_bfloat16* qbuf  = (__hip_bfloat16*)(ws + ((size_t)16 << 20));  //  8 MB
    __hip_bfloat16* kbuf  = (__hip_bfloat16*)(ws + ((size_t)24 << 20));  //  8 MB
    __hip_bfloat16* vbuf  = (__hip_bfloat16*)(ws + ((size_t)32 << 20));  //  8 MB (transposed)
    __hip_bfloat16* ctx   = (__hip_bfloat16*)(ws + ((size_t)40 << 20));  //  8 MB

    cvt_bf16_kernel<<<4096, 256, 0, stream>>>(emb, Xb, NROWS * MODEL);
    tcvt_kernel<<<dim3(QKVN / 32, MODEL / 32), dim3(32, 8), 0, stream>>>(w_qkv, Wqkvt, MODEL, QKVN);
    tcvt_kernel<<<dim3(MODEL / 32, MODEL / 32), dim3(32, 8), 0, stream>>>(w_out, Woutt, MODEL, MODEL);

    gemm_bt_kernel<0><<<dim3(QKVN / 128, NROWS / 128), 256, 0, stream>>>(
        Xb, Wqkvt, b_qkv, nullptr, qbuf, kbuf, vbuf, NROWS, QKVN, MODEL);

    attn_kernel<<<dim3(BATCH * NHEADS, SEQ / 256), 512, 0, stream>>>(qbuf, kbuf, vbuf, ctx);

    gemm_bt_kernel<1><<<dim3(MODEL / 128, NROWS / 128), 256, 0, stream>>>(
        ctx, Woutt, b_out, out, nullptr, nullptr, nullptr, NROWS, MODEL, MODEL);
}

// Round 3
// 228.053 us; speedup vs baseline: 1.6160x; 1.2428x over previous
//
#include <hip/hip_runtime.h>
#include <hip/hip_bf16.h>

#define MODEL 1024
#define NHEADS 16
#define HDIM 64
#define BATCH 2
#define SEQ 2048
#define NROWS (BATCH*SEQ)   // 4096
#define QKVN (3*MODEL)      // 3072
#define QSCALE 0.1803368801111204f  // 0.125 * log2(e): folded into Q; softmax uses exp2

typedef __bf16 bf16x8 __attribute__((ext_vector_type(8)));
typedef float f32x4 __attribute__((ext_vector_type(4)));
typedef float f32x16 __attribute__((ext_vector_type(16)));

#define GLDS(g, l) __builtin_amdgcn_global_load_lds( \
    (const __attribute__((address_space(1))) void*)(g), \
    (__attribute__((address_space(3))) void*)(l), 16, 0, 0)

__device__ inline unsigned cvtpk(float a, float b) {
    unsigned la = __builtin_bit_cast(unsigned short, __float2bfloat16(a));
    unsigned hb = __builtin_bit_cast(unsigned short, __float2bfloat16(b));
    return la | (hb << 16);
}

// fragment-major index for Q/K: [tile64(s>>6)][r2((s>>5)&1)*4+st(d>>4)][lane=(s&31)+32*((d>>3)&1)][j=d&7]
__device__ inline size_t qk_fidx(int s, int d) {
    return (((size_t)((s >> 6) * 8 + ((s >> 5) & 1) * 4 + (d >> 4)) * 64)
            + (s & 31) + ((d >> 3) & 1) * 32) * 8 + (d & 7);
}
// fragment-major index for V^T: [tile64(s>>6)][dr2(d>>5)*4+ks((s>>4)&3)][lane=(d&31)+32*((s>>3)&1)][j=s&7]
__device__ inline size_t v_fidx(int s, int d) {
    return (((size_t)((s >> 6) * 8 + (d >> 5) * 4 + ((s >> 4) & 3)) * 64)
            + (d & 31) + ((s >> 3) & 1) * 32) * 8 + (s & 7);
}

// ---------------- converters ----------------

__global__ __launch_bounds__(256) void cvt_bf16_kernel(const float* __restrict__ in,
                                                       __hip_bfloat16* __restrict__ out, int n) {
    int i = (blockIdx.x * 256 + threadIdx.x) * 4;
    if (i < n) {
        float4 v = *(const float4*)(in + i);
        out[i + 0] = __float2bfloat16(v.x);
        out[i + 1] = __float2bfloat16(v.y);
        out[i + 2] = __float2bfloat16(v.z);
        out[i + 3] = __float2bfloat16(v.w);
    }
}

// in[K][N] f32 -> out[N][K] bf16
__global__ __launch_bounds__(256) void tcvt_kernel(const float* __restrict__ in,
                                                   __hip_bfloat16* __restrict__ out, int K, int N) {
    __shared__ float tile[32][33];
    int tx = threadIdx.x, ty = threadIdx.y;
    int n0 = blockIdx.x * 32, k0 = blockIdx.y * 32;
#pragma unroll
    for (int i = 0; i < 4; ++i)
        tile[ty + i * 8][tx] = in[(size_t)(k0 + ty + i * 8) * N + n0 + tx];
    __syncthreads();
#pragma unroll
    for (int i = 0; i < 4; ++i)
        out[(size_t)(n0 + ty + i * 8) * K + k0 + tx] = __float2bfloat16(tile[tx][ty + i * 8]);
}

// ---------------- GEMM: C[M,N] = A[M,K] @ Bt[N,K]^T + bias ----------------
// EPI 0: scatter q (scaled) / k / v into MFMA-fragment-major buffers; EPI 1: fp32 C + bias.

template<int EPI>
__global__ __launch_bounds__(256) void gemm_bt_kernel(
    const __hip_bfloat16* __restrict__ A, const __hip_bfloat16* __restrict__ Bt,
    const float* __restrict__ bias, float* __restrict__ Cf,
    __hip_bfloat16* __restrict__ qb, __hip_bfloat16* __restrict__ kb,
    __hip_bfloat16* __restrict__ vb, int M, int N, int K)
{
    __shared__ __hip_bfloat16 As[128 * 32];
    __shared__ __hip_bfloat16 Bs[128 * 32];
    int tid = threadIdx.x;
    int lane = tid & 63, wv = tid >> 6;
    int wm = wv >> 1, wn = wv & 1;
    int g = lane >> 4, li = lane & 15;
    int row0 = blockIdx.y * 128, col0 = blockIdx.x * 128;

    f32x4 acc[4][4] = {};

    for (int kt = 0; kt < K; kt += 32) {
        __syncthreads();
#pragma unroll
        for (int s = 0; s < 2; ++s) {
            int idx = (s * 256 + tid) * 8;
            int r = idx >> 5, c = idx & 31;
            const __hip_bfloat16* ga = A + (size_t)(row0 + r) * K + kt + c;
            char* la = (char*)As + (size_t)(s * 4 + wv) * 1024;
            GLDS(ga, la);
            const __hip_bfloat16* gb = Bt + (size_t)(col0 + r) * K + kt + c;
            char* lb = (char*)Bs + (size_t)(s * 4 + wv) * 1024;
            GLDS(gb, lb);
        }
        __syncthreads();
        bf16x8 a[4], b[4];
#pragma unroll
        for (int m = 0; m < 4; ++m)
            a[m] = *(const bf16x8*)((const char*)As + (size_t)((wm * 64 + m * 16 + li) * 32 + g * 8) * 2);
#pragma unroll
        for (int n = 0; n < 4; ++n)
            b[n] = *(const bf16x8*)((const char*)Bs + (size_t)((wn * 64 + n * 16 + li) * 32 + g * 8) * 2);
#pragma unroll
        for (int m = 0; m < 4; ++m)
#pragma unroll
            for (int n = 0; n < 4; ++n)
                acc[m][n] = __builtin_amdgcn_mfma_f32_16x16x32_bf16(a[m], b[n], acc[m][n], 0, 0, 0);
    }

    if (EPI == 1) {
#pragma unroll
        for (int m = 0; m < 4; ++m) {
            int row = row0 + wm * 64 + m * 16 + g * 4;
#pragma unroll
            for (int n = 0; n < 4; ++n) {
                int col = col0 + wn * 64 + n * 16 + li;
                float bv = bias[col];
#pragma unroll
                for (int r = 0; r < 4; ++r)
                    Cf[(size_t)(row + r) * N + col] = acc[m][n][r] + bv;
            }
        }
    } else {
#pragma unroll
        for (int m = 0; m < 4; ++m)
#pragma unroll
            for (int r = 0; r < 4; ++r) {
                int row = row0 + wm * 64 + m * 16 + g * 4 + r;
                int b = row >> 11, s = row & 2047;
#pragma unroll
                for (int n = 0; n < 4; ++n) {
                    int col = col0 + wn * 64 + n * 16 + li;
                    float val = acc[m][n][r] + bias[col];
                    int h = col / 192;
                    int rem = col - h * 192;
                    int t = rem >> 6, d = rem & 63;
                    size_t base = (size_t)(b * NHEADS + h) * (SEQ * HDIM);
                    if (t == 0)
                        qb[base + qk_fidx(s, d)] = __float2bfloat16(val * QSCALE);
                    else if (t == 1)
                        kb[base + qk_fidx(s, d)] = __float2bfloat16(val);
                    else
                        vb[base + v_fidx(s, d)] = __float2bfloat16(val);
                }
            }
    }
}

// ---------------- flash attention (swapped-QK^T, fragment-major coalesced loads) ----------------
// grid: (B*H=32, SEQ/256=8), 512 threads = 8 waves, each wave owns 32 q-rows.
// All loads are 64-lane x 16B consecutive (1 KB/instr, 16 lines, fully used).

__global__ __launch_bounds__(512, 2) void attn_kernel(
    const __hip_bfloat16* __restrict__ qfb, const __hip_bfloat16* __restrict__ kfb,
    const __hip_bfloat16* __restrict__ vfb, __hip_bfloat16* __restrict__ ctx)
{
    int tid = threadIdx.x;
    int lane = tid & 63, w = tid >> 6;
    int qi = lane & 31, hi = lane >> 5;
    int bh = blockIdx.x;
    int b = bh >> 4, h = bh & 15;
    int q0 = blockIdx.y * 256 + w * 32;

    const bf16x8* QF = (const bf16x8*)qfb + (size_t)bh * 16384;  // 32 tiles * 512 frags-of-8
    const bf16x8* KF = (const bf16x8*)kfb + (size_t)bh * 16384;
    const bf16x8* VF = (const bf16x8*)vfb + (size_t)bh * 16384;

    bf16x8 qv[4];
    {
        int qt = q0 >> 6, qr2 = (q0 >> 5) & 1;
#pragma unroll
        for (int st = 0; st < 4; ++st)
            qv[st] = QF[(size_t)qt * 512 + (qr2 * 4 + st) * 64 + lane];
    }

    f32x16 o0 = {}, o1 = {};
    float m = -INFINITY, l = 0.f;

    bf16x8 kc[8], kn[8], vv[8];
#pragma unroll
    for (int f = 0; f < 8; ++f) kc[f] = KF[f * 64 + lane];

    for (int t = 0; t < 32; ++t) {
        __builtin_amdgcn_s_barrier();  // lockstep 8 waves -> L1 reuse of shared K/V tiles
        // issue this tile's V loads and next tile's K loads early; softmax hides latency
#pragma unroll
        for (int f = 0; f < 8; ++f) vv[f] = VF[(size_t)t * 512 + f * 64 + lane];
        int tn = (t + 1) & 31;
#pragma unroll
        for (int f = 0; f < 8; ++f) kn[f] = KF[(size_t)tn * 512 + f * 64 + lane];

        // S^T[k][q], one q-row per lane (Q pre-scaled by 0.125*log2e)
        f32x16 s0 = {}, s1 = {};
#pragma unroll
        for (int st = 0; st < 4; ++st) {
            s0 = __builtin_amdgcn_mfma_f32_32x32x16_bf16(kc[st], qv[st], s0, 0, 0, 0);
            s1 = __builtin_amdgcn_mfma_f32_32x32x16_bf16(kc[4 + st], qv[st], s1, 0, 0, 0);
        }

        // online softmax (log2 domain), tree-reduced
        float tm[8];
#pragma unroll
        for (int i = 0; i < 8; ++i)
            tm[i] = fmaxf(fmaxf(s0[i], s0[8 + i]), fmaxf(s1[i], s1[8 + i]));
#pragma unroll
        for (int i = 0; i < 4; ++i) tm[i] = fmaxf(tm[i], tm[4 + i]);
        float mx = fmaxf(fmaxf(tm[0], tm[1]), fmaxf(tm[2], tm[3]));
        mx = fmaxf(mx, __shfl_xor(mx, 32));
        float mn = fmaxf(m, mx);
        float al = exp2f(m - mn);
        m = mn;
#pragma unroll
        for (int i = 0; i < 16; ++i) s0[i] = exp2f(s0[i] - mn);
#pragma unroll
        for (int i = 0; i < 16; ++i) s1[i] = exp2f(s1[i] - mn);
        float ts[8];
#pragma unroll
        for (int i = 0; i < 8; ++i) ts[i] = (s0[i] + s0[8 + i]) + (s1[i] + s1[8 + i]);
#pragma unroll
        for (int i = 0; i < 4; ++i) ts[i] = ts[i] + ts[4 + i];
        float sum = (ts[0] + ts[1]) + (ts[2] + ts[3]);
        sum += __shfl_xor(sum, 32);
        l = l * al + sum;
#pragma unroll
        for (int i = 0; i < 16; ++i) { o0[i] *= al; o1[i] *= al; }

        // redistribute P^T into B-fragments (p lives in s0/s1)
        bf16x8 pb[4];
#pragma unroll
        for (int ks = 0; ks < 4; ++ks) {
            const f32x16& sv = (ks < 2) ? s0 : s1;
            const int base = (ks & 1) * 8;
            unsigned t0 = cvtpk(sv[base + 0], sv[base + 1]);
            unsigned t1 = cvtpk(sv[base + 2], sv[base + 3]);
            unsigned u0 = cvtpk(sv[base + 4], sv[base + 5]);
            unsigned u1 = cvtpk(sv[base + 6], sv[base + 7]);
            unsigned t0s = __shfl_xor(t0, 32);
            unsigned t1s = __shfl_xor(t1, 32);
            unsigned u0s = __shfl_xor(u0, 32);
            unsigned u1s = __shfl_xor(u1, 32);
            union { unsigned u[4]; bf16x8 v; } pk;
            pk.u[0] = hi ? u0s : t0;
            pk.u[1] = hi ? u1s : t1;
            pk.u[2] = hi ? u0 : t0s;
            pk.u[3] = hi ? u1 : t1s;
            pb[ks] = pk.v;
        }

        // O^T[d][q] += V^T[d][k] @ P^T[k][q]
#pragma unroll
        for (int ks = 0; ks < 4; ++ks) {
            o0 = __builtin_amdgcn_mfma_f32_32x32x16_bf16(vv[ks], pb[ks], o0, 0, 0, 0);
            o1 = __builtin_amdgcn_mfma_f32_32x32x16_bf16(vv[4 + ks], pb[ks], o1, 0, 0, 0);
        }
#pragma unroll
        for (int f = 0; f < 8; ++f) kc[f] = kn[f];
    }

    // epilogue: lane holds O^T[d][q=qi]; d = dt*32 + 8*rg + 4*hi + (0..3)
    float inv = 1.f / l;
    __hip_bfloat16* crow = ctx + ((size_t)(b * SEQ) + q0 + qi) * MODEL + h * HDIM;
#pragma unroll
    for (int rg = 0; rg < 4; ++rg) {
        uint2 pk0, pk1;
        pk0.x = cvtpk(o0[rg * 4 + 0] * inv, o0[rg * 4 + 1] * inv);
        pk0.y = cvtpk(o0[rg * 4 + 2] * inv, o0[rg * 4 + 3] * inv);
        pk1.x = cvtpk(o1[rg * 4 + 0] * inv, o1[rg * 4 + 1] * inv);
        pk1.y = cvtpk(o1[rg * 4 + 2] * inv, o1[rg * 4 + 3] * inv);
        *(uint2*)(crow + rg * 8 + hi * 4) = pk0;
        *(uint2*)(crow + 32 + rg * 8 + hi * 4) = pk1;
    }
}

// ---------------- launch ----------------

extern "C" void kernel_launch(void* const* d_in, const int* in_sizes, int n_in,
                              void* d_out, int out_size, void* d_ws, size_t ws_size,
                              hipStream_t stream) {
    const float* emb = (const float*)d_in[0];
    const float* w_qkv = (const float*)d_in[1];
    const float* b_qkv = (const float*)d_in[2];
    const float* w_out = (const float*)d_in[3];
    const float* b_out = (const float*)d_in[4];
    float* out = (float*)d_out;
    char* ws = (char*)d_ws;

    __hip_bfloat16* Xb    = (__hip_bfloat16*)(ws);                       //  8 MB
    __hip_bfloat16* Wqkvt = (__hip_bfloat16*)(ws + ((size_t)8  << 20));  //  6 MB
    __hip_bfloat16* Woutt = (__hip_bfloat16*)(ws + ((size_t)14 << 20));  //  2 MB
    __hip_bfloat16* qbuf  = (__hip_bfloat16*)(ws + ((size_t)16 << 20));  //  8 MB (frag-major)
    __hip_bfloat16* kbuf  = (__hip_bfloat16*)(ws + ((size_t)24 << 20));  //  8 MB (frag-major)
    __hip_bfloat16* vbuf  = (__hip_bfloat16*)(ws + ((size_t)32 << 20));  //  8 MB (frag-major V^T)
    __hip_bfloat16* ctx   = (__hip_bfloat16*)(ws + ((size_t)40 << 20));  //  8 MB

    cvt_bf16_kernel<<<4096, 256, 0, stream>>>(emb, Xb, NROWS * MODEL);
    tcvt_kernel<<<dim3(QKVN / 32, MODEL / 32), dim3(32, 8), 0, stream>>>(w_qkv, Wqkvt, MODEL, QKVN);
    tcvt_kernel<<<dim3(MODEL / 32, MODEL / 32), dim3(32, 8), 0, stream>>>(w_out, Woutt, MODEL, MODEL);

    gemm_bt_kernel<0><<<dim3(QKVN / 128, NROWS / 128), 256, 0, stream>>>(
        Xb, Wqkvt, b_qkv, nullptr, qbuf, kbuf, vbuf, NROWS, QKVN, MODEL);

    attn_kernel<<<dim3(BATCH * NHEADS, SEQ / 256), 512, 0, stream>>>(qbuf, kbuf, vbuf, ctx);

    gemm_bt_kernel<1><<<dim3(MODEL / 128, NROWS / 128), 256, 0, stream>>>(
        ctx, Woutt, b_out, out, nullptr, nullptr, nullptr, NROWS, MODEL, MODEL);
}

// Round 4
// 211.354 us; speedup vs baseline: 1.7436x; 1.0790x over previous
//
#include <hip/hip_runtime.h>
#include <hip/hip_bf16.h>

#define MODEL 1024
#define NHEADS 16
#define HDIM 64
#define BATCH 2
#define SEQ 2048
#define NROWS (BATCH*SEQ)   // 4096
#define QKVN (3*MODEL)      // 3072
#define QSCALE 0.1803368801111204f  // 0.125 * log2(e): folded into Q; softmax uses exp2

typedef __bf16 bf16x8 __attribute__((ext_vector_type(8)));
typedef float f32x4 __attribute__((ext_vector_type(4)));
typedef float f32x16 __attribute__((ext_vector_type(16)));

#define GLDS(g, l) __builtin_amdgcn_global_load_lds( \
    (const __attribute__((address_space(1))) void*)(g), \
    (__attribute__((address_space(3))) void*)(l), 16, 0, 0)

__device__ inline unsigned cvtpk(float lo, float hi) {  // lo -> bits[15:0], hi -> bits[31:16]
    unsigned r;
    asm("v_cvt_pk_bf16_f32 %0, %1, %2" : "=v"(r) : "v"(lo), "v"(hi));
    return r;
}

// fragment-major index for Q/K: [tile64(s>>6)][r2((s>>5)&1)*4+st(d>>4)][lane=(s&31)+32*((d>>3)&1)][j=d&7]
__device__ inline size_t qk_fidx(int s, int d) {
    return (((size_t)((s >> 6) * 8 + ((s >> 5) & 1) * 4 + (d >> 4)) * 64)
            + (s & 31) + ((d >> 3) & 1) * 32) * 8 + (d & 7);
}
// fragment-major index for V^T: [tile64(s>>6)][dr2(d>>5)*4+ks((s>>4)&3)][lane=(d&31)+32*((s>>3)&1)][j=s&7]
__device__ inline size_t v_fidx(int s, int d) {
    return (((size_t)((s >> 6) * 8 + (d >> 5) * 4 + ((s >> 4) & 3)) * 64)
            + (d & 31) + ((s >> 3) & 1) * 32) * 8 + (s & 7);
}

// ---------------- fused prep: emb->bf16, w_qkv^T->bf16, w_out^T->bf16 ----------------
// blocks [0,4096): cvt; [4096,7168): tcvt w_qkv (K=1024,N=3072); [7168,8192): tcvt w_out

__global__ __launch_bounds__(256) void prep_kernel(
    const float* __restrict__ emb, __hip_bfloat16* __restrict__ Xb,
    const float* __restrict__ wqkv, __hip_bfloat16* __restrict__ Wqkvt,
    const float* __restrict__ wout, __hip_bfloat16* __restrict__ Woutt)
{
    __shared__ float tile[32][33];
    int bid = blockIdx.x, tid = threadIdx.x;
    if (bid < 4096) {
        int i = (bid * 256 + tid) * 4;
        float4 v = *(const float4*)(emb + i);
        Xb[i + 0] = __float2bfloat16(v.x);
        Xb[i + 1] = __float2bfloat16(v.y);
        Xb[i + 2] = __float2bfloat16(v.z);
        Xb[i + 3] = __float2bfloat16(v.w);
        return;
    }
    const float* in; __hip_bfloat16* out; int K, N, n0, k0;
    if (bid < 7168) {
        int t = bid - 4096; in = wqkv; out = Wqkvt; K = MODEL; N = QKVN;
        n0 = (t % 96) * 32; k0 = (t / 96) * 32;
    } else {
        int t = bid - 7168; in = wout; out = Woutt; K = MODEL; N = MODEL;
        n0 = (t & 31) * 32; k0 = (t >> 5) * 32;
    }
    int tx = tid & 31, ty = tid >> 5;
#pragma unroll
    for (int i = 0; i < 4; ++i)
        tile[ty + i * 8][tx] = in[(size_t)(k0 + ty + i * 8) * N + n0 + tx];
    __syncthreads();
#pragma unroll
    for (int i = 0; i < 4; ++i)
        out[(size_t)(n0 + ty + i * 8) * K + k0 + tx] = __float2bfloat16(tile[tx][ty + i * 8]);
}

// ---------------- GEMM: C[M,N] = A[M,K] @ Bt[N,K]^T + bias ----------------
// EPI 0: scatter q (scaled) / k / v into MFMA-fragment-major buffers; EPI 1: fp32 C + bias.

template<int EPI>
__global__ __launch_bounds__(256) void gemm_bt_kernel(
    const __hip_bfloat16* __restrict__ A, const __hip_bfloat16* __restrict__ Bt,
    const float* __restrict__ bias, float* __restrict__ Cf,
    __hip_bfloat16* __restrict__ qb, __hip_bfloat16* __restrict__ kb,
    __hip_bfloat16* __restrict__ vb, int M, int N, int K)
{
    __shared__ __hip_bfloat16 As[128 * 32];
    __shared__ __hip_bfloat16 Bs[128 * 32];
    int tid = threadIdx.x;
    int lane = tid & 63, wv = tid >> 6;
    int wm = wv >> 1, wn = wv & 1;
    int g = lane >> 4, li = lane & 15;
    int row0 = blockIdx.y * 128, col0 = blockIdx.x * 128;

    f32x4 acc[4][4] = {};

    for (int kt = 0; kt < K; kt += 32) {
        __syncthreads();
#pragma unroll
        for (int s = 0; s < 2; ++s) {
            int idx = (s * 256 + tid) * 8;
            int r = idx >> 5, c = idx & 31;
            const __hip_bfloat16* ga = A + (size_t)(row0 + r) * K + kt + c;
            char* la = (char*)As + (size_t)(s * 4 + wv) * 1024;
            GLDS(ga, la);
            const __hip_bfloat16* gb = Bt + (size_t)(col0 + r) * K + kt + c;
            char* lb = (char*)Bs + (size_t)(s * 4 + wv) * 1024;
            GLDS(gb, lb);
        }
        __syncthreads();
        bf16x8 a[4], b[4];
#pragma unroll
        for (int m = 0; m < 4; ++m)
            a[m] = *(const bf16x8*)((const char*)As + (size_t)((wm * 64 + m * 16 + li) * 32 + g * 8) * 2);
#pragma unroll
        for (int n = 0; n < 4; ++n)
            b[n] = *(const bf16x8*)((const char*)Bs + (size_t)((wn * 64 + n * 16 + li) * 32 + g * 8) * 2);
#pragma unroll
        for (int m = 0; m < 4; ++m)
#pragma unroll
            for (int n = 0; n < 4; ++n)
                acc[m][n] = __builtin_amdgcn_mfma_f32_16x16x32_bf16(a[m], b[n], acc[m][n], 0, 0, 0);
    }

    if (EPI == 1) {
#pragma unroll
        for (int m = 0; m < 4; ++m) {
            int row = row0 + wm * 64 + m * 16 + g * 4;
#pragma unroll
            for (int n = 0; n < 4; ++n) {
                int col = col0 + wn * 64 + n * 16 + li;
                float bv = bias[col];
#pragma unroll
                for (int r = 0; r < 4; ++r)
                    Cf[(size_t)(row + r) * N + col] = acc[m][n][r] + bv;
            }
        }
    } else {
#pragma unroll
        for (int m = 0; m < 4; ++m)
#pragma unroll
            for (int r = 0; r < 4; ++r) {
                int row = row0 + wm * 64 + m * 16 + g * 4 + r;
                int b = row >> 11, s = row & 2047;
#pragma unroll
                for (int n = 0; n < 4; ++n) {
                    int col = col0 + wn * 64 + n * 16 + li;
                    float val = acc[m][n][r] + bias[col];
                    int h = col / 192;
                    int rem = col - h * 192;
                    int t = rem >> 6, d = rem & 63;
                    size_t base = (size_t)(b * NHEADS + h) * (SEQ * HDIM);
                    if (t == 0)
                        qb[base + qk_fidx(s, d)] = __float2bfloat16(val * QSCALE);
                    else if (t == 1)
                        kb[base + qk_fidx(s, d)] = __float2bfloat16(val);
                    else
                        vb[base + v_fidx(s, d)] = __float2bfloat16(val);
                }
            }
    }
}

// ---------------- flash attention (swapped-QK^T, split-KV, VALU-diet softmax) ----------------
// grid: (B*H=32, SEQ/64=32), 256 threads = 4 waves: (qg = w&1) x (kvh = w>>1).
// Each wave: 32 q-rows, 16 KV tiles (its half). Halves merged through LDS.

__global__ __launch_bounds__(256, 3) void attn_kernel(
    const __hip_bfloat16* __restrict__ qfb, const __hip_bfloat16* __restrict__ kfb,
    const __hip_bfloat16* __restrict__ vfb, __hip_bfloat16* __restrict__ ctx)
{
    __shared__ float Ms[2][64], Ls[2][64], Os[2][32][64];
    int tid = threadIdx.x;
    int lane = tid & 63, w = tid >> 6;
    int qg = w & 1, kvh = w >> 1;
    int qi = lane & 31, hi = lane >> 5;
    int bh = blockIdx.x;
    int b = bh >> 4, h = bh & 15;
    int q0 = blockIdx.y * 64 + qg * 32;

    const bf16x8* QF = (const bf16x8*)qfb + (size_t)bh * 16384;  // 32 tiles * 512 frags-of-8
    const bf16x8* KF = (const bf16x8*)kfb + (size_t)bh * 16384;
    const bf16x8* VF = (const bf16x8*)vfb + (size_t)bh * 16384;

    bf16x8 qv[4];
#pragma unroll
    for (int st = 0; st < 4; ++st)
        qv[st] = QF[(size_t)blockIdx.y * 512 + (qg * 4 + st) * 64 + lane];

    f32x16 o0 = {}, o1 = {};
    float m = -INFINITY, l = 0.f;

    for (int tt = 0; tt < 16; ++tt) {
        int t = kvh * 16 + tt;
        __builtin_amdgcn_s_barrier();  // keep waves tile-aligned for L1 reuse
        bf16x8 kc[8];
#pragma unroll
        for (int f = 0; f < 8; ++f) kc[f] = KF[(size_t)t * 512 + f * 64 + lane];

        // S^T[k][q], one q-row per lane (Q pre-scaled by 0.125*log2e)
        f32x16 s0 = {}, s1 = {};
#pragma unroll
        for (int st = 0; st < 4; ++st) {
            s0 = __builtin_amdgcn_mfma_f32_32x32x16_bf16(kc[st], qv[st], s0, 0, 0, 0);
            s1 = __builtin_amdgcn_mfma_f32_32x32x16_bf16(kc[4 + st], qv[st], s1, 0, 0, 0);
        }

        // V loads issued here; softmax below hides their latency
        bf16x8 vv[8];
#pragma unroll
        for (int f = 0; f < 8; ++f) vv[f] = VF[(size_t)t * 512 + f * 64 + lane];

        // online softmax (log2 domain), tree max, defer-max rescale (THR=8)
        float tm[8];
#pragma unroll
        for (int i = 0; i < 8; ++i)
            tm[i] = fmaxf(fmaxf(s0[i], s0[8 + i]), fmaxf(s1[i], s1[8 + i]));
#pragma unroll
        for (int i = 0; i < 4; ++i) tm[i] = fmaxf(tm[i], tm[4 + i]);
        float mx = fmaxf(fmaxf(tm[0], tm[1]), fmaxf(tm[2], tm[3]));
        mx = fmaxf(mx, __shfl_xor(mx, 32));
        if (__any(mx - m > 8.0f)) {
            float mn = fmaxf(m, mx);
            float al = __builtin_amdgcn_exp2f(m - mn);
            m = mn;
            l *= al;
#pragma unroll
            for (int i = 0; i < 16; ++i) { o0[i] *= al; o1[i] *= al; }
        }
#pragma unroll
        for (int i = 0; i < 16; ++i) s0[i] = __builtin_amdgcn_exp2f(s0[i] - m);
#pragma unroll
        for (int i = 0; i < 16; ++i) s1[i] = __builtin_amdgcn_exp2f(s1[i] - m);
        float ts[8];
#pragma unroll
        for (int i = 0; i < 8; ++i) ts[i] = (s0[i] + s0[8 + i]) + (s1[i] + s1[8 + i]);
#pragma unroll
        for (int i = 0; i < 4; ++i) ts[i] = ts[i] + ts[4 + i];
        float sum = (ts[0] + ts[1]) + (ts[2] + ts[3]);
        sum += __shfl_xor(sum, 32);
        l += sum;

        // P^T -> B-fragments: 16 cvt_pk + 8 half-wave shuffles (pre-selected payload)
        bf16x8 pb[4];
#pragma unroll
        for (int ks = 0; ks < 4; ++ks) {
            const f32x16& sv = (ks < 2) ? s0 : s1;
            const int base = (ks & 1) * 8;
            unsigned t0 = cvtpk(sv[base + 0], sv[base + 1]);
            unsigned t1 = cvtpk(sv[base + 2], sv[base + 3]);
            unsigned u0 = cvtpk(sv[base + 4], sv[base + 5]);
            unsigned u1 = cvtpk(sv[base + 6], sv[base + 7]);
            unsigned ra = __shfl_xor(hi ? t0 : u0, 32);  // lo gets partner t0; hi gets partner u0
            unsigned rb = __shfl_xor(hi ? t1 : u1, 32);
            union { unsigned u[4]; bf16x8 v; } pk;
            pk.u[0] = hi ? ra : t0;
            pk.u[1] = hi ? rb : t1;
            pk.u[2] = hi ? u0 : ra;
            pk.u[3] = hi ? u1 : rb;
            pb[ks] = pk.v;
        }

        // O^T[d][q] += V^T[d][k] @ P^T[k][q]
#pragma unroll
        for (int ks = 0; ks < 4; ++ks) {
            o0 = __builtin_amdgcn_mfma_f32_32x32x16_bf16(vv[ks], pb[ks], o0, 0, 0, 0);
            o1 = __builtin_amdgcn_mfma_f32_32x32x16_bf16(vv[4 + ks], pb[ks], o1, 0, 0, 0);
        }
    }

    // merge the two KV halves through LDS
    __syncthreads();
    if (kvh == 1) {
        Ms[qg][lane] = m; Ls[qg][lane] = l;
#pragma unroll
        for (int i = 0; i < 16; ++i) { Os[qg][i][lane] = o0[i]; Os[qg][16 + i][lane] = o1[i]; }
    }
    __syncthreads();
    if (kvh == 0) {
        float m2 = Ms[qg][lane], l2 = Ls[qg][lane];
        float mn = fmaxf(m, m2);
        float a = __builtin_amdgcn_exp2f(m - mn);
        float b2 = __builtin_amdgcn_exp2f(m2 - mn);
        float linv = 1.f / (l * a + l2 * b2);
        // epilogue: lane holds O^T[d][q=qi]; d = dt*32 + 8*rg + 4*hi + (0..3)
        __hip_bfloat16* crow = ctx + ((size_t)(b * SEQ) + q0 + qi) * MODEL + h * HDIM;
#pragma unroll
        for (int rg = 0; rg < 4; ++rg) {
            float c0[4], c1[4];
#pragma unroll
            for (int e = 0; e < 4; ++e) {
                int i = rg * 4 + e;
                c0[e] = (o0[i] * a + Os[qg][i][lane] * b2) * linv;
                c1[e] = (o1[i] * a + Os[qg][16 + i][lane] * b2) * linv;
            }
            uint2 pk0, pk1;
            pk0.x = cvtpk(c0[0], c0[1]); pk0.y = cvtpk(c0[2], c0[3]);
            pk1.x = cvtpk(c1[0], c1[1]); pk1.y = cvtpk(c1[2], c1[3]);
            *(uint2*)(crow + rg * 8 + hi * 4) = pk0;
            *(uint2*)(crow + 32 + rg * 8 + hi * 4) = pk1;
        }
    }
}

// ---------------- launch ----------------

extern "C" void kernel_launch(void* const* d_in, const int* in_sizes, int n_in,
                              void* d_out, int out_size, void* d_ws, size_t ws_size,
                              hipStream_t stream) {
    const float* emb = (const float*)d_in[0];
    const float* w_qkv = (const float*)d_in[1];
    const float* b_qkv = (const float*)d_in[2];
    const float* w_out = (const float*)d_in[3];
    const float* b_out = (const float*)d_in[4];
    float* out = (float*)d_out;
    char* ws = (char*)d_ws;

    __hip_bfloat16* Xb    = (__hip_bfloat16*)(ws);                       //  8 MB
    __hip_bfloat16* Wqkvt = (__hip_bfloat16*)(ws + ((size_t)8  << 20));  //  6 MB
    __hip_bfloat16* Woutt = (__hip_bfloat16*)(ws + ((size_t)14 << 20));  //  2 MB
    __hip_bfloat16* qbuf  = (__hip_bfloat16*)(ws + ((size_t)16 << 20));  //  8 MB (frag-major)
    __hip_bfloat16* kbuf  = (__hip_bfloat16*)(ws + ((size_t)24 << 20));  //  8 MB (frag-major)
    __hip_bfloat16* vbuf  = (__hip_bfloat16*)(ws + ((size_t)32 << 20));  //  8 MB (frag-major V^T)
    __hip_bfloat16* ctx   = (__hip_bfloat16*)(ws + ((size_t)40 << 20));  //  8 MB

    prep_kernel<<<8192, 256, 0, stream>>>(emb, Xb, w_qkv, Wqkvt, w_out, Woutt);

    gemm_bt_kernel<0><<<dim3(QKVN / 128, NROWS / 128), 256, 0, stream>>>(
        Xb, Wqkvt, b_qkv, nullptr, qbuf, kbuf, vbuf, NROWS, QKVN, MODEL);

    attn_kernel<<<dim3(BATCH * NHEADS, SEQ / 64), 256, 0, stream>>>(qbuf, kbuf, vbuf, ctx);

    gemm_bt_kernel<1><<<dim3(MODEL / 128, NROWS / 128), 256, 0, stream>>>(
        ctx, Woutt, b_out, out, nullptr, nullptr, nullptr, NROWS, MODEL, MODEL);
}

// Round 5
// 206.821 us; speedup vs baseline: 1.7819x; 1.0219x over previous
//
#include <hip/hip_runtime.h>
#include <hip/hip_bf16.h>

#define MODEL 1024
#define NHEADS 16
#define HDIM 64
#define BATCH 2
#define SEQ 2048
#define NROWS (BATCH*SEQ)   // 4096
#define QKVN (3*MODEL)      // 3072
#define QSCALE 0.1803368801111204f  // 0.125 * log2(e): folded into Q; softmax uses exp2

typedef __bf16 bf16x8 __attribute__((ext_vector_type(8)));
typedef float f32x4 __attribute__((ext_vector_type(4)));
typedef float f32x16 __attribute__((ext_vector_type(16)));

#define GLDS(g, l) __builtin_amdgcn_global_load_lds( \
    (const __attribute__((address_space(1))) void*)(g), \
    (__attribute__((address_space(3))) void*)(l), 16, 0, 0)

__device__ inline unsigned cvtpk(float lo, float hi) {  // lo -> bits[15:0], hi -> bits[31:16]
    unsigned r;
    asm("v_cvt_pk_bf16_f32 %0, %1, %2" : "=v"(r) : "v"(lo), "v"(hi));
    return r;
}

// fragment-major index for Q/K: [tile64(s>>6)][r2((s>>5)&1)*4+st(d>>4)][lane=(s&31)+32*((d>>3)&1)][j=d&7]
__device__ inline size_t qk_fidx(int s, int d) {
    return (((size_t)((s >> 6) * 8 + ((s >> 5) & 1) * 4 + (d >> 4)) * 64)
            + (s & 31) + ((d >> 3) & 1) * 32) * 8 + (d & 7);
}
// fragment-major index for V^T: [tile64(s>>6)][dr2(d>>5)*4+ks((s>>4)&3)][lane=(d&31)+32*((s>>3)&1)][j=s&7]
__device__ inline size_t v_fidx(int s, int d) {
    return (((size_t)((s >> 6) * 8 + (d >> 5) * 4 + ((s >> 4) & 3)) * 64)
            + (d & 31) + ((s >> 3) & 1) * 32) * 8 + (s & 7);
}

// ---------------- fused prep: emb->bf16, w_qkv^T->bf16, w_out^T->bf16 ----------------
// blocks [0,4096): cvt; [4096,7168): tcvt w_qkv (K=1024,N=3072); [7168,8192): tcvt w_out

__global__ __launch_bounds__(256) void prep_kernel(
    const float* __restrict__ emb, __hip_bfloat16* __restrict__ Xb,
    const float* __restrict__ wqkv, __hip_bfloat16* __restrict__ Wqkvt,
    const float* __restrict__ wout, __hip_bfloat16* __restrict__ Woutt)
{
    __shared__ float tile[32][33];
    int bid = blockIdx.x, tid = threadIdx.x;
    if (bid < 4096) {
        int i = (bid * 256 + tid) * 4;
        float4 v = *(const float4*)(emb + i);
        Xb[i + 0] = __float2bfloat16(v.x);
        Xb[i + 1] = __float2bfloat16(v.y);
        Xb[i + 2] = __float2bfloat16(v.z);
        Xb[i + 3] = __float2bfloat16(v.w);
        return;
    }
    const float* in; __hip_bfloat16* out; int K, N, n0, k0;
    if (bid < 7168) {
        int t = bid - 4096; in = wqkv; out = Wqkvt; K = MODEL; N = QKVN;
        n0 = (t % 96) * 32; k0 = (t / 96) * 32;
    } else {
        int t = bid - 7168; in = wout; out = Woutt; K = MODEL; N = MODEL;
        n0 = (t & 31) * 32; k0 = (t >> 5) * 32;
    }
    int tx = tid & 31, ty = tid >> 5;
#pragma unroll
    for (int i = 0; i < 4; ++i)
        tile[ty + i * 8][tx] = in[(size_t)(k0 + ty + i * 8) * N + n0 + tx];
    __syncthreads();
#pragma unroll
    for (int i = 0; i < 4; ++i)
        out[(size_t)(n0 + ty + i * 8) * K + k0 + tx] = __float2bfloat16(tile[tx][ty + i * 8]);
}

// ---------------- GEMM: C[M,N] = A[M,K] @ Bt[N,K]^T + bias ----------------
// EPI 0: scatter q (scaled) / k / v into MFMA-fragment-major buffers; EPI 1: fp32 C + bias.

template<int EPI>
__global__ __launch_bounds__(256) void gemm_bt_kernel(
    const __hip_bfloat16* __restrict__ A, const __hip_bfloat16* __restrict__ Bt,
    const float* __restrict__ bias, float* __restrict__ Cf,
    __hip_bfloat16* __restrict__ qb, __hip_bfloat16* __restrict__ kb,
    __hip_bfloat16* __restrict__ vb, int M, int N, int K)
{
    __shared__ __hip_bfloat16 As[128 * 32];
    __shared__ __hip_bfloat16 Bs[128 * 32];
    int tid = threadIdx.x;
    int lane = tid & 63, wv = tid >> 6;
    int wm = wv >> 1, wn = wv & 1;
    int g = lane >> 4, li = lane & 15;
    int row0 = blockIdx.y * 128, col0 = blockIdx.x * 128;

    f32x4 acc[4][4] = {};

    for (int kt = 0; kt < K; kt += 32) {
        __syncthreads();
#pragma unroll
        for (int s = 0; s < 2; ++s) {
            int idx = (s * 256 + tid) * 8;
            int r = idx >> 5, c = idx & 31;
            const __hip_bfloat16* ga = A + (size_t)(row0 + r) * K + kt + c;
            char* la = (char*)As + (size_t)(s * 4 + wv) * 1024;
            GLDS(ga, la);
            const __hip_bfloat16* gb = Bt + (size_t)(col0 + r) * K + kt + c;
            char* lb = (char*)Bs + (size_t)(s * 4 + wv) * 1024;
            GLDS(gb, lb);
        }
        __syncthreads();
        bf16x8 a[4], b[4];
#pragma unroll
        for (int m = 0; m < 4; ++m)
            a[m] = *(const bf16x8*)((const char*)As + (size_t)((wm * 64 + m * 16 + li) * 32 + g * 8) * 2);
#pragma unroll
        for (int n = 0; n < 4; ++n)
            b[n] = *(const bf16x8*)((const char*)Bs + (size_t)((wn * 64 + n * 16 + li) * 32 + g * 8) * 2);
#pragma unroll
        for (int m = 0; m < 4; ++m)
#pragma unroll
            for (int n = 0; n < 4; ++n)
                acc[m][n] = __builtin_amdgcn_mfma_f32_16x16x32_bf16(a[m], b[n], acc[m][n], 0, 0, 0);
    }

    if (EPI == 1) {
#pragma unroll
        for (int m = 0; m < 4; ++m) {
            int row = row0 + wm * 64 + m * 16 + g * 4;
#pragma unroll
            for (int n = 0; n < 4; ++n) {
                int col = col0 + wn * 64 + n * 16 + li;
                float bv = bias[col];
#pragma unroll
                for (int r = 0; r < 4; ++r)
                    Cf[(size_t)(row + r) * N + col] = acc[m][n][r] + bv;
            }
        }
    } else {
#pragma unroll
        for (int m = 0; m < 4; ++m)
#pragma unroll
            for (int r = 0; r < 4; ++r) {
                int row = row0 + wm * 64 + m * 16 + g * 4 + r;
                int b = row >> 11, s = row & 2047;
#pragma unroll
                for (int n = 0; n < 4; ++n) {
                    int col = col0 + wn * 64 + n * 16 + li;
                    float val = acc[m][n][r] + bias[col];
                    int h = col / 192;
                    int rem = col - h * 192;
                    int t = rem >> 6, d = rem & 63;
                    size_t base = (size_t)(b * NHEADS + h) * (SEQ * HDIM);
                    if (t == 0)
                        qb[base + qk_fidx(s, d)] = __float2bfloat16(val * QSCALE);
                    else if (t == 1)
                        kb[base + qk_fidx(s, d)] = __float2bfloat16(val);
                    else
                        vb[base + v_fidx(s, d)] = __float2bfloat16(val);
                }
            }
    }
}

// ---------------- flash attention (swapped-QK^T, split-KV, KVBLK=32, 4 waves/SIMD) ----------------
// grid: (B*H=32, SEQ/64=32) = 1024 blocks = exactly 4 blocks/CU (one residency round).
// 256 threads = 4 waves: (qg = w&1) x (kvh = w>>1). Each wave: 32 q-rows, 32 KV tiles of 32.
// <=128 unified regs/wave (launch_bounds min 4 waves/EU) -> 16 waves/CU.

__global__ __launch_bounds__(256, 4) void attn_kernel(
    const __hip_bfloat16* __restrict__ qfb, const __hip_bfloat16* __restrict__ kfb,
    const __hip_bfloat16* __restrict__ vfb, __hip_bfloat16* __restrict__ ctx)
{
    __shared__ float Ms[2][64], Ls[2][64], Os[2][32][64];
    int tid = threadIdx.x;
    int lane = tid & 63, w = tid >> 6;
    int qg = w & 1, kvh = w >> 1;
    int qi = lane & 31, hi = lane >> 5;
    int bh = blockIdx.x;
    int b = bh >> 4, h = bh & 15;
    int q0 = blockIdx.y * 64 + qg * 32;

    const bf16x8* QF = (const bf16x8*)qfb + (size_t)bh * 16384;  // 32 tiles * 512 frags-of-8
    const bf16x8* KF = (const bf16x8*)kfb + (size_t)bh * 16384;
    const bf16x8* VF = (const bf16x8*)vfb + (size_t)bh * 16384;

    bf16x8 qv[4];
#pragma unroll
    for (int st = 0; st < 4; ++st)
        qv[st] = QF[(size_t)blockIdx.y * 512 + (qg * 4 + st) * 64 + lane];

    f32x16 o0 = {}, o1 = {};
    float m = -INFINITY, l = 0.f;

    // preload K fragments for first tile of this wave's half
    bf16x8 kc[4], kn[4];
    {
        int t32 = kvh * 32, t64 = t32 >> 1, rh = t32 & 1;
#pragma unroll
        for (int st = 0; st < 4; ++st)
            kc[st] = KF[(size_t)t64 * 512 + (rh * 4 + st) * 64 + lane];
    }

    for (int tt = 0; tt < 32; ++tt) {
        int t32 = kvh * 32 + tt;
        int t64 = t32 >> 1, rh = t32 & 1;
        __builtin_amdgcn_s_barrier();  // align waves for cache reuse across qg pair

        // QK^T: S^T[k][q], one q-row per lane (Q pre-scaled by 0.125*log2e)
        f32x16 s = {};
#pragma unroll
        for (int st = 0; st < 4; ++st)
            s = __builtin_amdgcn_mfma_f32_32x32x16_bf16(kc[st], qv[st], s, 0, 0, 0);

        // issue V loads (this tile) + K loads (next tile); softmax hides latency
        bf16x8 vv[4];
#pragma unroll
        for (int dr = 0; dr < 2; ++dr)
#pragma unroll
            for (int ksl = 0; ksl < 2; ++ksl)
                vv[dr * 2 + ksl] = VF[(size_t)t64 * 512 + (dr * 4 + rh * 2 + ksl) * 64 + lane];
        {
            int tp = (tt < 31) ? t32 + 1 : t32;
            int p64 = tp >> 1, ph = tp & 1;
#pragma unroll
            for (int st = 0; st < 4; ++st)
                kn[st] = KF[(size_t)p64 * 512 + (ph * 4 + st) * 64 + lane];
        }

        // online softmax (log2 domain), tree max, defer-max rescale (THR=8)
        float tm[8];
#pragma unroll
        for (int i = 0; i < 8; ++i) tm[i] = fmaxf(s[i], s[8 + i]);
#pragma unroll
        for (int i = 0; i < 4; ++i) tm[i] = fmaxf(tm[i], tm[4 + i]);
        float mx = fmaxf(fmaxf(tm[0], tm[1]), fmaxf(tm[2], tm[3]));
        mx = fmaxf(mx, __shfl_xor(mx, 32));
        if (__any(mx - m > 8.0f)) {
            float mn = fmaxf(m, mx);
            float al = __builtin_amdgcn_exp2f(m - mn);
            m = mn;
            l *= al;
#pragma unroll
            for (int i = 0; i < 16; ++i) { o0[i] *= al; o1[i] *= al; }
        }
#pragma unroll
        for (int i = 0; i < 16; ++i) s[i] = __builtin_amdgcn_exp2f(s[i] - m);
        float ts[8];
#pragma unroll
        for (int i = 0; i < 8; ++i) ts[i] = s[i] + s[8 + i];
#pragma unroll
        for (int i = 0; i < 4; ++i) ts[i] = ts[i] + ts[4 + i];
        float sum = (ts[0] + ts[1]) + (ts[2] + ts[3]);
        sum += __shfl_xor(sum, 32);
        l += sum;

        // P^T -> B-fragments: 8 cvt_pk + 4 half-wave shuffles (pre-selected payload)
        bf16x8 pb[2];
#pragma unroll
        for (int ksl = 0; ksl < 2; ++ksl) {
            const int base = ksl * 8;
            unsigned t0 = cvtpk(s[base + 0], s[base + 1]);
            unsigned t1 = cvtpk(s[base + 2], s[base + 3]);
            unsigned u0 = cvtpk(s[base + 4], s[base + 5]);
            unsigned u1 = cvtpk(s[base + 6], s[base + 7]);
            unsigned ra = __shfl_xor(hi ? t0 : u0, 32);
            unsigned rb = __shfl_xor(hi ? t1 : u1, 32);
            union { unsigned u[4]; bf16x8 v; } pk;
            pk.u[0] = hi ? ra : t0;
            pk.u[1] = hi ? rb : t1;
            pk.u[2] = hi ? u0 : ra;
            pk.u[3] = hi ? u1 : rb;
            pb[ksl] = pk.v;
        }

        // O^T[d][q] += V^T[d][k] @ P^T[k][q]
        o0 = __builtin_amdgcn_mfma_f32_32x32x16_bf16(vv[0], pb[0], o0, 0, 0, 0);
        o0 = __builtin_amdgcn_mfma_f32_32x32x16_bf16(vv[1], pb[1], o0, 0, 0, 0);
        o1 = __builtin_amdgcn_mfma_f32_32x32x16_bf16(vv[2], pb[0], o1, 0, 0, 0);
        o1 = __builtin_amdgcn_mfma_f32_32x32x16_bf16(vv[3], pb[1], o1, 0, 0, 0);

#pragma unroll
        for (int st = 0; st < 4; ++st) kc[st] = kn[st];
    }

    // merge the two KV halves through LDS
    __syncthreads();
    if (kvh == 1) {
        Ms[qg][lane] = m; Ls[qg][lane] = l;
#pragma unroll
        for (int i = 0; i < 16; ++i) { Os[qg][i][lane] = o0[i]; Os[qg][16 + i][lane] = o1[i]; }
    }
    __syncthreads();
    if (kvh == 0) {
        float m2 = Ms[qg][lane], l2 = Ls[qg][lane];
        float mn = fmaxf(m, m2);
        float a = __builtin_amdgcn_exp2f(m - mn);
        float b2 = __builtin_amdgcn_exp2f(m2 - mn);
        float linv = 1.f / (l * a + l2 * b2);
        // epilogue: lane holds O^T[d][q=qi]; d = dt*32 + 8*rg + 4*hi + (0..3)
        __hip_bfloat16* crow = ctx + ((size_t)(b * SEQ) + q0 + qi) * MODEL + h * HDIM;
#pragma unroll
        for (int rg = 0; rg < 4; ++rg) {
            float c0[4], c1[4];
#pragma unroll
            for (int e = 0; e < 4; ++e) {
                int i = rg * 4 + e;
                c0[e] = (o0[i] * a + Os[qg][i][lane] * b2) * linv;
                c1[e] = (o1[i] * a + Os[qg][16 + i][lane] * b2) * linv;
            }
            uint2 pk0, pk1;
            pk0.x = cvtpk(c0[0], c0[1]); pk0.y = cvtpk(c0[2], c0[3]);
            pk1.x = cvtpk(c1[0], c1[1]); pk1.y = cvtpk(c1[2], c1[3]);
            *(uint2*)(crow + rg * 8 + hi * 4) = pk0;
            *(uint2*)(crow + 32 + rg * 8 + hi * 4) = pk1;
        }
    }
}

// ---------------- launch ----------------

extern "C" void kernel_launch(void* const* d_in, const int* in_sizes, int n_in,
                              void* d_out, int out_size, void* d_ws, size_t ws_size,
                              hipStream_t stream) {
    const float* emb = (const float*)d_in[0];
    const float* w_qkv = (const float*)d_in[1];
    const float* b_qkv = (const float*)d_in[2];
    const float* w_out = (const float*)d_in[3];
    const float* b_out = (const float*)d_in[4];
    float* out = (float*)d_out;
    char* ws = (char*)d_ws;

    __hip_bfloat16* Xb    = (__hip_bfloat16*)(ws);                       //  8 MB
    __hip_bfloat16* Wqkvt = (__hip_bfloat16*)(ws + ((size_t)8  << 20));  //  6 MB
    __hip_bfloat16* Woutt = (__hip_bfloat16*)(ws + ((size_t)14 << 20));  //  2 MB
    __hip_bfloat16* qbuf  = (__hip_bfloat16*)(ws + ((size_t)16 << 20));  //  8 MB (frag-major)
    __hip_bfloat16* kbuf  = (__hip_bfloat16*)(ws + ((size_t)24 << 20));  //  8 MB (frag-major)
    __hip_bfloat16* vbuf  = (__hip_bfloat16*)(ws + ((size_t)32 << 20));  //  8 MB (frag-major V^T)
    __hip_bfloat16* ctx   = (__hip_bfloat16*)(ws + ((size_t)40 << 20));  //  8 MB

    prep_kernel<<<8192, 256, 0, stream>>>(emb, Xb, w_qkv, Wqkvt, w_out, Woutt);

    gemm_bt_kernel<0><<<dim3(QKVN / 128, NROWS / 128), 256, 0, stream>>>(
        Xb, Wqkvt, b_qkv, nullptr, qbuf, kbuf, vbuf, NROWS, QKVN, MODEL);

    attn_kernel<<<dim3(BATCH * NHEADS, SEQ / 64), 256, 0, stream>>>(qbuf, kbuf, vbuf, ctx);

    gemm_bt_kernel<1><<<dim3(MODEL / 128, NROWS / 128), 256, 0, stream>>>(
        ctx, Woutt, b_out, out, nullptr, nullptr, nullptr, NROWS, MODEL, MODEL);
}